// Round 5
// baseline (283.317 us; speedup 1.0000x reference)
//
#include <hip/hip_runtime.h>
#include <hip/hip_bf16.h>
#include <math.h>

#define BB 16
#define TT 2048
#define VV 512

typedef __attribute__((ext_vector_type(8))) short short8;
typedef __attribute__((ext_vector_type(4))) float floatx4;

static __device__ inline ushort f2bf(float f) {
  __hip_bfloat16 h = __float2bfloat16(f);
  return *(ushort*)&h;
}
static __device__ inline float bf2f(ushort u) {
  unsigned int x = ((unsigned int)u) << 16;
  return __uint_as_float(x);
}

// async 16B global->LDS DMA. LDS dest = wave-uniform base + lane*16.
static __device__ __forceinline__ void cp16(const void* g, void* l) {
  __builtin_amdgcn_global_load_lds((const __attribute__((address_space(1))) void*)g,
                                   (__attribute__((address_space(3))) void*)l, 16, 0, 0);
}

// Static-balance tile mapping for k_gemm_gt (round-robin co-set sums 136).
static __device__ __forceinline__ void balance_map(int y, int z, int* t_t, int* b) {
  const int r = y & 3, q = z >> 2;
  int t = (q == 0) ? r : (q == 1) ? (r + 8) : (q == 2) ? (7 - r) : (15 - r);
  *t_t = t;
  *b = ((z & 3) << 2) | (y >> 2);
}

// P chunk base: c in 0..14; chunks 0..4 alias dead WqT/PE/M region, 5..14 in
// the region previously used for a2 (proven ws bound 201,850,880 bytes).
static __device__ __forceinline__ const ushort* pc_base(const ushort* Plo,
                                                        const ushort* Phi, int c) {
  return (c < 5) ? Plo + (size_t)c * 4194304UL : Phi + (size_t)(c - 5) * 4194304UL;
}

// ---------------- builders ----------------

__global__ __launch_bounds__(256) void k_transpose_wq(const float* __restrict__ Wq,
                                                      ushort* __restrict__ WqT) {
  int u = blockIdx.x;
  for (int v = threadIdx.x; v < VV; v += blockDim.x)
    WqT[u * VV + v] = f2bf(Wq[(size_t)v * VV + u]);
}

__global__ __launch_bounds__(256) void k_build_pe(const float* __restrict__ h,
                                                  ushort* __restrict__ PE) {
  int t = blockIdx.x;
  ushort* out = PE + (size_t)t * TT;
  for (int p = threadIdx.x; p < TT; p += blockDim.x)
    out[p] = (p <= t) ? f2bf(h[t - p]) : (ushort)0;
}

// M[b,u,p] = WqT[u, idx[b,p]] ; VvT[b,j,s] = Wv[j, idx[b,s]]
__global__ __launch_bounds__(256) void k_build_mv(const int* __restrict__ idx,
                                                  const float* __restrict__ Wv,
                                                  const ushort* __restrict__ WqT,
                                                  ushort* __restrict__ M,
                                                  ushort* __restrict__ VvT) {
  int bv = blockIdx.x;
  int b = bv >> 9, v = bv & (VV - 1);
  __shared__ float wrow[VV];
  __shared__ ushort qrow[VV];
  for (int u = threadIdx.x; u < VV; u += blockDim.x) {
    wrow[u] = Wv[(size_t)v * VV + u];
    qrow[u] = WqT[(size_t)v * VV + u];
  }
  __syncthreads();
  const int* row = idx + b * TT;
  ushort* om = M + (size_t)bv * TT;
  ushort* ov = VvT + (size_t)bv * TT;
  for (int s4 = threadIdx.x * 4; s4 < TT; s4 += blockDim.x * 4) {
    int4 iv = *(const int4*)(row + s4);
    ushort4 m, w;
    m.x = qrow[iv.x];  w.x = f2bf(wrow[iv.x]);
    m.y = qrow[iv.y];  w.y = f2bf(wrow[iv.y]);
    m.z = qrow[iv.z];  w.z = f2bf(wrow[iv.z]);
    m.w = qrow[iv.w];  w.w = f2bf(wrow[iv.w]);
    *(ushort4*)(om + s4) = m;
    *(ushort4*)(ov + s4) = w;
  }
}

// ---------------- 128x128 MFMA GEMM core (3-slot counted pipeline) --------

#define GEMM_PRELUDE()                                                         \
  __shared__ __attribute__((aligned(16))) short As[3 * 128 * 32];              \
  __shared__ __attribute__((aligned(16))) short Bs[3 * 128 * 32];              \
  const int tid = threadIdx.x;                                                 \
  const int lane = tid & 63;                                                   \
  const int wm = (tid >> 6) & 1, wn = tid >> 7;                                \
  const int quad = lane >> 4, ln = lane & 15;                                  \
  const int rr = tid >> 2;                                                     \
  const int cg = (((tid & 3) ^ (rr & 3)) << 3);                                \
  short* a_dst = &As[tid * 8];                                                 \
  short* b_dst = &Bs[tid * 8];                                                 \
  const short* ap[4];                                                          \
  const short* bp[4];                                                          \
  _Pragma("unroll") for (int i = 0; i < 4; i++)                                \
      ap[i] = &As[(wm * 64 + i * 16 + ln) * 32 + ((quad ^ (ln & 3)) << 3)];    \
  _Pragma("unroll") for (int j = 0; j < 4; j++)                                \
      bp[j] = &Bs[(wn * 64 + j * 16 + ln) * 32 + ((quad ^ (ln & 3)) << 3)];

#define GEMM_STAGE(c, PA0, PA1, PB0, PB1)                                      \
  {                                                                            \
    const int _o = (c) << 12;                                                  \
    cp16((PA0), a_dst + _o);                                                   \
    cp16((PA1), a_dst + _o + 2048);                                            \
    cp16((PB0), b_dst + _o);                                                   \
    cp16((PB1), b_dst + _o + 2048);                                            \
  }

#define GEMM_COMPUTE(c)                                                        \
  {                                                                            \
    const int _o = (c) << 12;                                                  \
    short8 af[4], bfr[4];                                                      \
    _Pragma("unroll") for (int i = 0; i < 4; i++)                              \
        af[i] = *(const short8*)(ap[i] + _o);                                  \
    _Pragma("unroll") for (int j = 0; j < 4; j++)                              \
        bfr[j] = *(const short8*)(bp[j] + _o);                                 \
    _Pragma("unroll") for (int i = 0; i < 4; i++)                              \
        _Pragma("unroll") for (int j = 0; j < 4; j++)                          \
            acc[i][j] = __builtin_amdgcn_mfma_f32_16x16x32_bf16(               \
                af[i], bfr[j], acc[i][j], 0, 0, 0);                            \
  }

#define ZERO_ACC()                                                             \
  _Pragma("unroll") for (int i = 0; i < 4; i++)                                \
      _Pragma("unroll") for (int j = 0; j < 4; j++)                            \
          acc[i][j] = (floatx4){0.f, 0.f, 0.f, 0.f};

#define PIPE_LOOP(NK, STAGE_AT)                                                \
  {                                                                            \
    STAGE_AT(0, 0);                                                            \
    STAGE_AT(1, 1);                                                            \
    int cur = 0, pf = 2;                                                       \
    _Pragma("unroll 1") for (int kt = 0; kt < (NK); ++kt) {                    \
      if (kt + 1 < (NK)) {                                                     \
        asm volatile("s_waitcnt vmcnt(4)" ::: "memory");                       \
      } else {                                                                 \
        asm volatile("s_waitcnt vmcnt(0)" ::: "memory");                       \
      }                                                                        \
      __builtin_amdgcn_sched_barrier(0);                                       \
      __builtin_amdgcn_s_barrier();                                            \
      __builtin_amdgcn_sched_barrier(0);                                       \
      if (kt + 2 < (NK)) STAGE_AT(pf, kt + 2);                                 \
      __builtin_amdgcn_sched_barrier(0);                                       \
      __builtin_amdgcn_s_setprio(1);                                           \
      GEMM_COMPUTE(cur);                                                       \
      __builtin_amdgcn_s_setprio(0);                                           \
      cur = (cur == 2) ? 0 : cur + 1;                                          \
      pf = (pf == 2) ? 0 : pf + 1;                                             \
    }                                                                          \
  }

// GT[b,u,s] = sum_p M[b,u,p] * PE[s,p]  (causal K-extent)
__global__ __launch_bounds__(256) void k_gemm_gt(const ushort* __restrict__ M,
                                                 const ushort* __restrict__ PE,
                                                 ushort* __restrict__ GT) {
  int s_t, b;
  balance_map(blockIdx.y, blockIdx.z, &s_t, &b);
  const int u_t = blockIdx.x;
  const int u0 = u_t << 7, s0 = s_t << 7;
  const int nk = (s_t << 2) + 4;
  GEMM_PRELUDE();
  const ushort* a_src0 = M + ((size_t)((b << 9) + u0 + rr)) * TT + cg;
  const ushort* a_src1 = a_src0 + (size_t)64 * TT;
  const ushort* b_src0 = PE + (size_t)(s0 + rr) * TT + cg;
  const ushort* b_src1 = b_src0 + (size_t)64 * TT;
  floatx4 acc[4][4];
  ZERO_ACC();
#define SA_GT(c, k)                                                            \
  GEMM_STAGE(c, a_src0 + ((k) << 5), a_src1 + ((k) << 5), b_src0 + ((k) << 5), \
             b_src1 + ((k) << 5))
  PIPE_LOOP(nk, SA_GT);
#undef SA_GT
#pragma unroll
  for (int i = 0; i < 4; i++)
#pragma unroll
    for (int j = 0; j < 4; j++) {
      const int rowb = u0 + wm * 64 + i * 16 + quad * 4;
      const int col = s0 + wn * 64 + j * 16 + ln;
#pragma unroll
      for (int r = 0; r < 4; r++)
        GT[((size_t)((b << 9) + rowb + r)) * TT + col] = f2bf(acc[i][j][r]);
    }
}

// Pre-masked diagonal tiles: a2d[b][t_t][r][c] = (c<=r) ? GT[b, idx[b,t0+r], t0+c] : 0
__global__ __launch_bounds__(256) void k_diag(const int* __restrict__ idx,
                                              const ushort* __restrict__ GT,
                                              ushort* __restrict__ a2d) {
  const int t_t = blockIdx.x, b = blockIdx.y;
  const int t0 = t_t << 7;
  ushort* outt = a2d + (((size_t)(b << 4) + t_t) << 14);
  for (int e = threadIdx.x; e < 2048; e += 256) {
    const int r = e >> 4;
    const int c8 = (e & 15) << 3;
    const int u = idx[(b << 11) + t0 + r];
    const ushort* src = GT + ((size_t)((b << 9) + u)) * TT + t0 + c8;
    ushort4 lo = *(const ushort4*)(src);
    ushort4 hi = *(const ushort4*)(src + 4);
    ushort vals[8] = {lo.x, lo.y, lo.z, lo.w, hi.x, hi.y, hi.z, hi.w};
    ushort o[8];
#pragma unroll
    for (int k = 0; k < 8; ++k) o[k] = (c8 + k <= r) ? vals[k] : (ushort)0;
    *(ushort4*)(outt + r * 128 + c8) = *(ushort4*)&o[0];
    *(ushort4*)(outt + r * 128 + c8 + 4) = *(ushort4*)&o[4];
  }
}

// k_pfx: prefix GEMMs over token-ids.
// P_c[b,u,j] = sum_{s < 128(c+1)} GT[b,u,s] * VvT[b,j,s], c = 0..14.
// Tile 128(u) x 64(j), K = 1920 (60 uniform k-steps); running f32 accumulator
// written to bf16 P_c every 4 k-steps. Grid 512 uniform blocks (residency 2);
// co-pair {c, c+256} shares (b, jh) -> shared B-tile in L2.
__global__ __launch_bounds__(256) void k_pfx(const ushort* __restrict__ GT,
                                             const ushort* __restrict__ VvT,
                                             ushort* __restrict__ Plo,
                                             ushort* __restrict__ Phi) {
  const int b = blockIdx.x, jh = blockIdx.y, u_t = blockIdx.z;
  const int u0 = u_t << 7, j0 = jh << 6;
  __shared__ __attribute__((aligned(16))) short As[2 * 128 * 32];
  __shared__ __attribute__((aligned(16))) short Bs[2 * 64 * 32];
  const int tid = threadIdx.x, lane = tid & 63;
  const int wv = tid >> 6;
  const int wm = wv >> 1, wn = wv & 1;  // 2 row-halves x 2 col-halves
  const int quad = lane >> 4, ln = lane & 15;
  const int rr = tid >> 2;
  const int cg = (((tid & 3) ^ (rr & 3)) << 3);
  short* a_dst = &As[tid * 8];
  short* b_dst = &Bs[tid * 8];
  const short* ap[4];
  const short* bp[2];
#pragma unroll
  for (int i = 0; i < 4; i++)
    ap[i] = &As[(wm * 64 + i * 16 + ln) * 32 + ((quad ^ (ln & 3)) << 3)];
#pragma unroll
  for (int j = 0; j < 2; j++)
    bp[j] = &Bs[(wn * 32 + j * 16 + ln) * 32 + ((quad ^ (ln & 3)) << 3)];
  const ushort* a0 = GT + ((size_t)((b << 9) + u0 + rr)) * TT + cg;
  const ushort* a1 = a0 + (size_t)64 * TT;
  const ushort* b0 = VvT + ((size_t)((b << 9) + j0 + rr)) * TT + cg;
  floatx4 acc[4][2];
#pragma unroll
  for (int i = 0; i < 4; i++)
#pragma unroll
    for (int j = 0; j < 2; j++) acc[i][j] = (floatx4){0.f, 0.f, 0.f, 0.f};

#define PSTAGE(c, k)                                                           \
  {                                                                            \
    cp16(a0 + ((k) << 5), a_dst + ((c) << 12));                                \
    cp16(a1 + ((k) << 5), a_dst + ((c) << 12) + 2048);                         \
    cp16(b0 + ((k) << 5), b_dst + ((c) << 11));                                \
  }
  PSTAGE(0, 0);
  __syncthreads();
  int cur = 0;
#pragma unroll 1
  for (int kt = 0; kt < 60; ++kt) {
    if (kt + 1 < 60) PSTAGE(cur ^ 1, kt + 1);
    {
      short8 af[4], bfr[2];
#pragma unroll
      for (int i = 0; i < 4; i++) af[i] = *(const short8*)(ap[i] + (cur << 12));
#pragma unroll
      for (int j = 0; j < 2; j++) bfr[j] = *(const short8*)(bp[j] + (cur << 11));
#pragma unroll
      for (int i = 0; i < 4; i++)
#pragma unroll
        for (int j = 0; j < 2; j++)
          acc[i][j] = __builtin_amdgcn_mfma_f32_16x16x32_bf16(af[i], bfr[j],
                                                              acc[i][j], 0, 0, 0);
    }
    if ((kt & 3) == 3) {  // prefix chunk c complete -> write P_c
      const int c = kt >> 2;
      ushort* P = (ushort*)pc_base(Plo, Phi, c);
#pragma unroll
      for (int i = 0; i < 4; i++)
#pragma unroll
        for (int j = 0; j < 2; j++) {
          const int row = u0 + wm * 64 + i * 16 + quad * 4;
          const int col = j0 + wn * 32 + j * 16 + ln;
#pragma unroll
          for (int r = 0; r < 4; r++)
            P[((size_t)((b << 9) + row + r) << 9) + col] = f2bf(acc[i][j][r]);
        }
    }
    __syncthreads();
    cur ^= 1;
  }
#undef PSTAGE
}

// k_gd: out[b,t,j] = gather(P_{t_t-1}[b, idx[b,t], j]) + a2d[b,t_t] @ VvT-chunk
// Uniform 4-k-step blocks; co-set {c,c+256,...} shares (b,t_t) -> shared A.
__global__ __launch_bounds__(256) void k_gd(const int* __restrict__ idx,
                                            const ushort* __restrict__ a2d,
                                            const ushort* __restrict__ VvT,
                                            const ushort* __restrict__ Plo,
                                            const ushort* __restrict__ Phi,
                                            float* __restrict__ out) {
  const int b = blockIdx.x, t_t = blockIdx.y, j_t = blockIdx.z;
  const int t0 = t_t << 7, j0 = j_t << 7;
  GEMM_PRELUDE();
  const ushort* ad0 = a2d + (((size_t)(b << 4) + t_t) << 14) + (size_t)rr * 128 + cg;
  const ushort* ad1 = ad0 + (size_t)64 * 128;
  const ushort* b_src0 = VvT + ((size_t)((b << 9) + j0 + rr)) * TT + t0 + cg;
  const ushort* b_src1 = b_src0 + (size_t)64 * TT;
  floatx4 acc[4][4];
  ZERO_ACC();
#define SA_GD(c, k)                                                            \
  GEMM_STAGE(c, ad0 + ((k) << 5), ad1 + ((k) << 5), b_src0 + ((k) << 5),       \
             b_src1 + ((k) << 5))
  PIPE_LOOP(4, SA_GD);
#undef SA_GD
  const ushort* P =
      (t_t > 0) ? pc_base(Plo, Phi, t_t - 1) : (const ushort*)nullptr;
#pragma unroll
  for (int i = 0; i < 4; i++)
#pragma unroll
    for (int j = 0; j < 4; j++) {
      const int rowb = wm * 64 + i * 16 + quad * 4;
      const int col = j0 + wn * 64 + j * 16 + ln;
#pragma unroll
      for (int r = 0; r < 4; r++) {
        const int t = t0 + rowb + r;
        float v = acc[i][j][r];
        if (t_t > 0) {
          const int u = idx[(b << 11) + t];
          v += bf2f(P[((size_t)((b << 9) + u) << 9) + col]);
        }
        out[((size_t)((b << 11) + t)) * VV + col] = v;
      }
    }
}

extern "C" void kernel_launch(void* const* d_in, const int* in_sizes, int n_in,
                              void* d_out, int out_size, void* d_ws, size_t ws_size,
                              hipStream_t stream) {
  const int* idx = (const int*)d_in[0];
  const float* pos_table = (const float*)d_in[1];
  const float* Wq = (const float*)d_in[2];
  const float* Wv = (const float*)d_in[3];
  float* out = (float*)d_out;

  char* ws = (char*)d_ws;
  // ws layout (bytes):
  //   WqT bf16 (V,V)        :         0 ..    524288   (dead after k_build_mv)
  //   PE  bf16 (T,T)        :    524288 ..   8912896   (dead after k_gemm_gt)
  //   M   bf16 (B,V,T)      :   8912896 ..  42467328   (dead after k_gemm_gt)
  //   VvT bf16 (B,V,T)      :  42467328 ..  76021760
  //   GT  bf16 (B,V,T)      :  76021760 .. 109576192
  //   a2d bf16 (B,16,128^2) : 109576192 .. 117964800
  //   P chunks c=0..4 alias [0 .. 41943040) (WqT/PE/M dead by k_pfx)
  //   P chunks c=5..14      : 117964800 .. 201850880  (proven ws bound)
  ushort* WqT = (ushort*)(ws);
  ushort* PE = (ushort*)(ws + 524288UL);
  ushort* M = (ushort*)(ws + 8912896UL);
  ushort* VvT = (ushort*)(ws + 42467328UL);
  ushort* GT = (ushort*)(ws + 76021760UL);
  ushort* a2d = (ushort*)(ws + 109576192UL);
  ushort* Plo = (ushort*)(ws);
  ushort* Phi = (ushort*)(ws + 117964800UL);

  k_transpose_wq<<<dim3(VV), 256, 0, stream>>>(Wq, WqT);
  k_build_pe<<<dim3(TT), 256, 0, stream>>>(pos_table, PE);
  k_build_mv<<<dim3(BB * VV), 256, 0, stream>>>(idx, Wv, WqT, M, VvT);
  k_gemm_gt<<<dim3(4, 16, BB), 256, 0, stream>>>(M, PE, GT);
  k_diag<<<dim3(16, BB), 256, 0, stream>>>(idx, GT, a2d);
  k_pfx<<<dim3(BB, 8, 4), 256, 0, stream>>>(GT, VvT, Plo, Phi);
  k_gd<<<dim3(BB, 16, 4), 256, 0, stream>>>(idx, a2d, VvT, Plo, Phi, out);
}

// Round 6
// 237.015 us; speedup vs baseline: 1.1954x; 1.1954x over previous
//
#include <hip/hip_runtime.h>
#include <hip/hip_bf16.h>
#include <math.h>

#define BB 16
#define TT 2048
#define VV 512

typedef __attribute__((ext_vector_type(8))) short short8;
typedef __attribute__((ext_vector_type(4))) float floatx4;

static __device__ inline ushort f2bf(float f) {
  __hip_bfloat16 h = __float2bfloat16(f);
  return *(ushort*)&h;
}

// async 16B global->LDS DMA. LDS dest = wave-uniform base + lane*16.
static __device__ __forceinline__ void cp16(const void* g, void* l) {
  __builtin_amdgcn_global_load_lds((const __attribute__((address_space(1))) void*)g,
                                   (__attribute__((address_space(3))) void*)l, 16, 0, 0);
}

// ---------------- builders ----------------

__global__ __launch_bounds__(256) void k_transpose_wq(const float* __restrict__ Wq,
                                                      ushort* __restrict__ WqT) {
  int u = blockIdx.x;
  for (int v = threadIdx.x; v < VV; v += blockDim.x)
    WqT[u * VV + v] = f2bf(Wq[(size_t)v * VV + u]);
}

__global__ __launch_bounds__(256) void k_build_pe(const float* __restrict__ h,
                                                  ushort* __restrict__ PE) {
  int t = blockIdx.x;
  ushort* out = PE + (size_t)t * TT;
  for (int p = threadIdx.x; p < TT; p += blockDim.x)
    out[p] = (p <= t) ? f2bf(h[t - p]) : (ushort)0;
}

// M[b,u,p] = WqT[u, idx[b,p]] ; VvT[b,j,s] = Wv[j, idx[b,s]]
__global__ __launch_bounds__(256) void k_build_mv(const int* __restrict__ idx,
                                                  const float* __restrict__ Wv,
                                                  const ushort* __restrict__ WqT,
                                                  ushort* __restrict__ M,
                                                  ushort* __restrict__ VvT) {
  int bv = blockIdx.x;
  int b = bv >> 9, v = bv & (VV - 1);
  __shared__ float wrow[VV];
  __shared__ ushort qrow[VV];
  for (int u = threadIdx.x; u < VV; u += blockDim.x) {
    wrow[u] = Wv[(size_t)v * VV + u];
    qrow[u] = WqT[(size_t)v * VV + u];
  }
  __syncthreads();
  const int* row = idx + b * TT;
  ushort* om = M + (size_t)bv * TT;
  ushort* ov = VvT + (size_t)bv * TT;
  for (int s4 = threadIdx.x * 4; s4 < TT; s4 += blockDim.x * 4) {
    int4 iv = *(const int4*)(row + s4);
    ushort4 m, w;
    m.x = qrow[iv.x];  w.x = f2bf(wrow[iv.x]);
    m.y = qrow[iv.y];  w.y = f2bf(wrow[iv.y]);
    m.z = qrow[iv.z];  w.z = f2bf(wrow[iv.z]);
    m.w = qrow[iv.w];  w.w = f2bf(wrow[iv.w]);
    *(ushort4*)(om + s4) = m;
    *(ushort4*)(ov + s4) = w;
  }
}

// ---------------- 128x128 MFMA GEMM core ----------------
// 3-slot LDS ring, 2-deep prefetch, counted vmcnt (never 0 in steady state),
// single raw s_barrier per iter, setprio around MFMA cluster (R4-verified).
// Pair-block scheduling: every block runs two complementary causal tiles
// (t, 15-t) sequentially -> uniform 68 k-steps per block, grid 512 = 2/CU
// constant residency, no tail, panel-sharing blocks dispatch-adjacent.

#define GEMM_PRELUDE()                                                         \
  __shared__ __attribute__((aligned(16))) short As[3 * 128 * 32];              \
  __shared__ __attribute__((aligned(16))) short Bs[3 * 128 * 32];              \
  const int tid = threadIdx.x;                                                 \
  const int lane = tid & 63;                                                   \
  const int wm = (tid >> 6) & 1, wn = tid >> 7;                                \
  const int quad = lane >> 4, ln = lane & 15;                                  \
  const int rr = tid >> 2;                                                     \
  const int cg = (((tid & 3) ^ (rr & 3)) << 3);                                \
  short* a_dst = &As[tid * 8];                                                 \
  short* b_dst = &Bs[tid * 8];                                                 \
  const short* ap[4];                                                          \
  const short* bp[4];                                                          \
  _Pragma("unroll") for (int i = 0; i < 4; i++)                                \
      ap[i] = &As[(wm * 64 + i * 16 + ln) * 32 + ((quad ^ (ln & 3)) << 3)];    \
  _Pragma("unroll") for (int j = 0; j < 4; j++)                                \
      bp[j] = &Bs[(wn * 64 + j * 16 + ln) * 32 + ((quad ^ (ln & 3)) << 3)];

#define GEMM_STAGE(c, PA0, PA1, PB0, PB1)                                      \
  {                                                                            \
    const int _o = (c) << 12;                                                  \
    cp16((PA0), a_dst + _o);                                                   \
    cp16((PA1), a_dst + _o + 2048);                                            \
    cp16((PB0), b_dst + _o);                                                   \
    cp16((PB1), b_dst + _o + 2048);                                            \
  }

#define GEMM_COMPUTE(c)                                                        \
  {                                                                            \
    const int _o = (c) << 12;                                                  \
    short8 af[4], bfr[4];                                                      \
    _Pragma("unroll") for (int i = 0; i < 4; i++)                              \
        af[i] = *(const short8*)(ap[i] + _o);                                  \
    _Pragma("unroll") for (int j = 0; j < 4; j++)                              \
        bfr[j] = *(const short8*)(bp[j] + _o);                                 \
    _Pragma("unroll") for (int i = 0; i < 4; i++)                              \
        _Pragma("unroll") for (int j = 0; j < 4; j++)                          \
            acc[i][j] = __builtin_amdgcn_mfma_f32_16x16x32_bf16(               \
                af[i], bfr[j], acc[i][j], 0, 0, 0);                            \
  }

#define ZERO_ACC()                                                             \
  _Pragma("unroll") for (int i = 0; i < 4; i++)                                \
      _Pragma("unroll") for (int j = 0; j < 4; j++)                            \
          acc[i][j] = (floatx4){0.f, 0.f, 0.f, 0.f};

#define PIPE_LOOP(NK, STAGE_AT)                                                \
  {                                                                            \
    STAGE_AT(0, 0);                                                            \
    STAGE_AT(1, 1);                                                            \
    int cur = 0, pf = 2;                                                       \
    _Pragma("unroll 1") for (int kt = 0; kt < (NK); ++kt) {                    \
      if (kt + 1 < (NK)) {                                                     \
        asm volatile("s_waitcnt vmcnt(4)" ::: "memory");                       \
      } else {                                                                 \
        asm volatile("s_waitcnt vmcnt(0)" ::: "memory");                       \
      }                                                                        \
      __builtin_amdgcn_sched_barrier(0);                                       \
      __builtin_amdgcn_s_barrier();                                            \
      __builtin_amdgcn_sched_barrier(0);                                       \
      if (kt + 2 < (NK)) STAGE_AT(pf, kt + 2);                                 \
      __builtin_amdgcn_sched_barrier(0);                                       \
      __builtin_amdgcn_s_setprio(1);                                           \
      GEMM_COMPUTE(cur);                                                       \
      __builtin_amdgcn_s_setprio(0);                                           \
      cur = (cur == 2) ? 0 : cur + 1;                                          \
      pf = (pf == 2) ? 0 : pf + 1;                                             \
    }                                                                          \
  }

// GT[b,u,s] = sum_p M[b,u,p] * PE[s,p]  (causal K-extent: p < 128*(s_t+1))
// Pair-block: s-tiles (p, 15-p) in one block -> uniform 68 k-steps.
__global__ __launch_bounds__(256) void k_gemm_gt(const ushort* __restrict__ M,
                                                 const ushort* __restrict__ PE,
                                                 ushort* __restrict__ GT) {
  const int u_t = blockIdx.x, pr = blockIdx.y, b = blockIdx.z;
  const int u0 = u_t << 7;
  GEMM_PRELUDE();
  const ushort* a_base0 = M + ((size_t)((b << 9) + u0 + rr)) * TT + cg;
  const ushort* a_base1 = a_base0 + (size_t)64 * TT;
  floatx4 acc[4][4];
#pragma unroll 1
  for (int half = 0; half < 2; ++half) {
    const int s_t = half ? (15 - pr) : pr;
    const int s0 = s_t << 7;
    const int nk = (s_t << 2) + 4;
    const ushort* a_src0 = a_base0;
    const ushort* a_src1 = a_base1;
    const ushort* b_src0 = PE + (size_t)(s0 + rr) * TT + cg;
    const ushort* b_src1 = b_src0 + (size_t)64 * TT;
    ZERO_ACC();
#define SA_GT(c, k)                                                            \
  GEMM_STAGE(c, a_src0 + ((k) << 5), a_src1 + ((k) << 5), b_src0 + ((k) << 5), \
             b_src1 + ((k) << 5))
    PIPE_LOOP(nk, SA_GT);
#undef SA_GT
#pragma unroll
    for (int i = 0; i < 4; i++)
#pragma unroll
      for (int j = 0; j < 4; j++) {
        const int rowb = u0 + wm * 64 + i * 16 + quad * 4;
        const int col = s0 + wn * 64 + j * 16 + ln;
#pragma unroll
        for (int r = 0; r < 4; r++)
          GT[((size_t)((b << 9) + rowb + r)) * TT + col] = f2bf(acc[i][j][r]);
      }
    __syncthreads();  // slot-0/1 readers done before next half's re-stage
  }
}

// Pre-masked diagonal tiles: a2d[b][t_t][r][c] = (c<=r) ? GT[b, idx[b,t0+r], t0+c] : 0
__global__ __launch_bounds__(256) void k_diag(const int* __restrict__ idx,
                                              const ushort* __restrict__ GT,
                                              ushort* __restrict__ a2d) {
  const int t_t = blockIdx.x, b = blockIdx.y;
  const int t0 = t_t << 7;
  ushort* outt = a2d + (((size_t)(b << 4) + t_t) << 14);
  for (int e = threadIdx.x; e < 2048; e += 256) {
    const int r = e >> 4;
    const int c8 = (e & 15) << 3;
    const int u = idx[(b << 11) + t0 + r];
    const ushort* src = GT + ((size_t)((b << 9) + u)) * TT + t0 + c8;
    ushort4 lo = *(const ushort4*)(src);
    ushort4 hi = *(const ushort4*)(src + 4);
    ushort vals[8] = {lo.x, lo.y, lo.z, lo.w, hi.x, hi.y, hi.z, hi.w};
    ushort o[8];
#pragma unroll
    for (int k = 0; k < 8; ++k) o[k] = (c8 + k <= r) ? vals[k] : (ushort)0;
    *(ushort4*)(outt + r * 128 + c8) = *(ushort4*)&o[0];
    *(ushort4*)(outt + r * 128 + c8 + 4) = *(ushort4*)&o[4];
  }
}

// logits[b,t,j] = sum_{s<=t} GT[b, idx[b,t], s] * VvT[b,j,s]
// Pair-block: t-tiles (p, 15-p) sequentially; per half, K-loop unified:
// kt < nk_main -> gathered GT rows; kt >= nk_main -> pre-masked diag tile.
__global__ __launch_bounds__(256) void k_gemm2(const int* __restrict__ idx,
                                               const ushort* __restrict__ GT,
                                               const ushort* __restrict__ a2d,
                                               const ushort* __restrict__ VvT,
                                               float* __restrict__ out) {
  const int j_t = blockIdx.x, pr = blockIdx.y, b = blockIdx.z;
  const int j0 = j_t << 7;
  GEMM_PRELUDE();
  const ushort* b_base0 = VvT + ((size_t)((b << 9) + j0 + rr)) * TT + cg;
  const ushort* b_base1 = b_base0 + (size_t)64 * TT;
  floatx4 acc[4][4];
#pragma unroll 1
  for (int half = 0; half < 2; ++half) {
    const int t_t = half ? (15 - pr) : pr;
    const int t0 = t_t << 7;
    const int nk_main = t_t << 2;
    const int nk = nk_main + 4;
    const int u0 = idx[(b << 11) + t0 + rr];
    const int u1 = idx[(b << 11) + t0 + rr + 64];
    const ushort* a_src0 = GT + ((size_t)(b << 9) + u0) * TT + cg;
    const ushort* a_src1 = GT + ((size_t)(b << 9) + u1) * TT + cg;
    const ushort* b_src0 = b_base0;
    const ushort* b_src1 = b_base1;
    const ushort* ad0 =
        a2d + (((size_t)(b << 4) + t_t) << 14) + (size_t)rr * 128 + cg;
    const ushort* ad1 = ad0 + (size_t)64 * 128;
    ZERO_ACC();
#define SA_G2(c, k)                                                            \
  GEMM_STAGE(c,                                                                \
             (k) < nk_main ? a_src0 + ((k) << 5) : ad0 + (((k) - nk_main) << 5), \
             (k) < nk_main ? a_src1 + ((k) << 5) : ad1 + (((k) - nk_main) << 5), \
             b_src0 + ((k) << 5), b_src1 + ((k) << 5))
    PIPE_LOOP(nk, SA_G2);
#undef SA_G2
#pragma unroll
    for (int i = 0; i < 4; i++)
#pragma unroll
      for (int j = 0; j < 4; j++) {
        const int rowb = t0 + wm * 64 + i * 16 + quad * 4;
        const int col = j0 + wn * 64 + j * 16 + ln;
#pragma unroll
        for (int r = 0; r < 4; r++)
          out[((size_t)((b << 11) + rowb + r)) * VV + col] = acc[i][j][r];
      }
    __syncthreads();  // slot-0/1 readers done before next half's re-stage
  }
}

extern "C" void kernel_launch(void* const* d_in, const int* in_sizes, int n_in,
                              void* d_out, int out_size, void* d_ws, size_t ws_size,
                              hipStream_t stream) {
  const int* idx = (const int*)d_in[0];
  const float* pos_table = (const float*)d_in[1];
  const float* Wq = (const float*)d_in[2];
  const float* Wv = (const float*)d_in[3];
  float* out = (float*)d_out;

  char* ws = (char*)d_ws;
  // ws layout (bytes):
  //   WqT bf16 (V,V)        :         0 ..    524288
  //   PE  bf16 (T,T)        :    524288 ..   8912896
  //   M   bf16 (B,V,T)      :   8912896 ..  42467328
  //   VvT bf16 (B,V,T)      :  42467328 ..  76021760
  //   GT  bf16 (B,V,T)      :  76021760 .. 109576192
  //   a2d bf16 (B,16,128^2) : 109576192 .. 117964800
  ushort* WqT = (ushort*)(ws);
  ushort* PE = (ushort*)(ws + 524288UL);
  ushort* M = (ushort*)(ws + 8912896UL);
  ushort* VvT = (ushort*)(ws + 42467328UL);
  ushort* GT = (ushort*)(ws + 76021760UL);
  ushort* a2d = (ushort*)(ws + 109576192UL);

  k_transpose_wq<<<dim3(VV), 256, 0, stream>>>(Wq, WqT);
  k_build_pe<<<dim3(TT), 256, 0, stream>>>(pos_table, PE);
  k_build_mv<<<dim3(BB * VV), 256, 0, stream>>>(idx, Wv, WqT, M, VvT);
  k_gemm_gt<<<dim3(4, 8, BB), 256, 0, stream>>>(M, PE, GT);
  k_diag<<<dim3(16, BB), 256, 0, stream>>>(idx, GT, a2d);
  k_gemm2<<<dim3(4, 8, BB), 256, 0, stream>>>(idx, GT, a2d, VvT, out);
}

// Round 7
// 207.898 us; speedup vs baseline: 1.3628x; 1.1401x over previous
//
#include <hip/hip_runtime.h>
#include <hip/hip_bf16.h>
#include <math.h>

#define BB 16
#define TT 2048
#define VV 512

typedef __attribute__((ext_vector_type(8))) short short8;
typedef __attribute__((ext_vector_type(4))) float floatx4;

static __device__ inline ushort f2bf(float f) {
  __hip_bfloat16 h = __float2bfloat16(f);
  return *(ushort*)&h;
}

// async 16B global->LDS DMA. LDS dest = wave-uniform base + lane*16;
// global source is per-lane.
static __device__ __forceinline__ void cp16(const void* g, void* l) {
  __builtin_amdgcn_global_load_lds((const __attribute__((address_space(1))) void*)g,
                                   (__attribute__((address_space(3))) void*)l, 16, 0, 0);
}

// XCD-explicit decode: default dispatch puts block h on XCD h%8 (m157/m204).
// bits [2:0] = b_lo (XCD pin), [4:3] = col-tile, [7:5] = pr, [8] = b_hi.
// => all A/B/a2d traffic for batch b lands in exactly one XCD's L2.
static __device__ __forceinline__ void xcd_map(int h, int* b, int* ct, int* pr) {
  *b = (h & 7) | ((h >> 8) << 3);
  *ct = (h >> 3) & 3;
  *pr = (h >> 5) & 7;
}

// ---------------- builders ----------------

__global__ __launch_bounds__(256) void k_transpose_wq(const float* __restrict__ Wq,
                                                      ushort* __restrict__ WqT) {
  int u = blockIdx.x;
  for (int v = threadIdx.x; v < VV; v += blockDim.x)
    WqT[u * VV + v] = f2bf(Wq[(size_t)v * VV + u]);
}

__global__ __launch_bounds__(256) void k_build_pe(const float* __restrict__ h,
                                                  ushort* __restrict__ PE) {
  int t = blockIdx.x;
  ushort* out = PE + (size_t)t * TT;
  for (int p = threadIdx.x; p < TT; p += blockDim.x)
    out[p] = (p <= t) ? f2bf(h[t - p]) : (ushort)0;
}

// M[b,u,p] = WqT[u, idx[b,p]] ; VvT[b,j,s] = Wv[j, idx[b,s]]
__global__ __launch_bounds__(256) void k_build_mv(const int* __restrict__ idx,
                                                  const float* __restrict__ Wv,
                                                  const ushort* __restrict__ WqT,
                                                  ushort* __restrict__ M,
                                                  ushort* __restrict__ VvT) {
  int bv = blockIdx.x;
  int b = bv >> 9, v = bv & (VV - 1);
  __shared__ float wrow[VV];
  __shared__ ushort qrow[VV];
  for (int u = threadIdx.x; u < VV; u += blockDim.x) {
    wrow[u] = Wv[(size_t)v * VV + u];
    qrow[u] = WqT[(size_t)v * VV + u];
  }
  __syncthreads();
  const int* row = idx + b * TT;
  ushort* om = M + (size_t)bv * TT;
  ushort* ov = VvT + (size_t)bv * TT;
  for (int s4 = threadIdx.x * 4; s4 < TT; s4 += blockDim.x * 4) {
    int4 iv = *(const int4*)(row + s4);
    ushort4 m, w;
    m.x = qrow[iv.x];  w.x = f2bf(wrow[iv.x]);
    m.y = qrow[iv.y];  w.y = f2bf(wrow[iv.y]);
    m.z = qrow[iv.z];  w.z = f2bf(wrow[iv.z]);
    m.w = qrow[iv.w];  w.w = f2bf(wrow[iv.w]);
    *(ushort4*)(om + s4) = m;
    *(ushort4*)(ov + s4) = w;
  }
}

// ---------------- 128x128 MFMA GEMM core ----------------
// 3-slot LDS ring, 2-deep prefetch, counted vmcnt (never 0 in steady state),
// single raw s_barrier per iter, setprio around MFMA cluster (R4-verified).
// Pair-block scheduling: every block runs two complementary causal tiles
// (pr, 15-pr) sequentially -> uniform 68 k-steps, grid 512 = 2/CU constant
// residency, no tail. XCD locality comes from xcd_map, not co-residency.

#define GEMM_PRELUDE()                                                         \
  __shared__ __attribute__((aligned(16))) short As[3 * 128 * 32];              \
  __shared__ __attribute__((aligned(16))) short Bs[3 * 128 * 32];              \
  const int tid = threadIdx.x;                                                 \
  const int lane = tid & 63;                                                   \
  const int wm = (tid >> 6) & 1, wn = tid >> 7;                                \
  const int quad = lane >> 4, ln = lane & 15;                                  \
  const int rr = tid >> 2;                                                     \
  const int cg = (((tid & 3) ^ (rr & 3)) << 3);                                \
  short* a_dst = &As[tid * 8];                                                 \
  short* b_dst = &Bs[tid * 8];                                                 \
  const short* ap[4];                                                          \
  const short* bp[4];                                                          \
  _Pragma("unroll") for (int i = 0; i < 4; i++)                                \
      ap[i] = &As[(wm * 64 + i * 16 + ln) * 32 + ((quad ^ (ln & 3)) << 3)];    \
  _Pragma("unroll") for (int j = 0; j < 4; j++)                                \
      bp[j] = &Bs[(wn * 64 + j * 16 + ln) * 32 + ((quad ^ (ln & 3)) << 3)];

#define GEMM_STAGE(c, PA0, PA1, PB0, PB1)                                      \
  {                                                                            \
    const int _o = (c) << 12;                                                  \
    cp16((PA0), a_dst + _o);                                                   \
    cp16((PA1), a_dst + _o + 2048);                                            \
    cp16((PB0), b_dst + _o);                                                   \
    cp16((PB1), b_dst + _o + 2048);                                            \
  }

#define GEMM_COMPUTE(c)                                                        \
  {                                                                            \
    const int _o = (c) << 12;                                                  \
    short8 af[4], bfr[4];                                                      \
    _Pragma("unroll") for (int i = 0; i < 4; i++)                              \
        af[i] = *(const short8*)(ap[i] + _o);                                  \
    _Pragma("unroll") for (int j = 0; j < 4; j++)                              \
        bfr[j] = *(const short8*)(bp[j] + _o);                                 \
    _Pragma("unroll") for (int i = 0; i < 4; i++)                              \
        _Pragma("unroll") for (int j = 0; j < 4; j++)                          \
            acc[i][j] = __builtin_amdgcn_mfma_f32_16x16x32_bf16(               \
                af[i], bfr[j], acc[i][j], 0, 0, 0);                            \
  }

#define ZERO_ACC()                                                             \
  _Pragma("unroll") for (int i = 0; i < 4; i++)                                \
      _Pragma("unroll") for (int j = 0; j < 4; j++)                            \
          acc[i][j] = (floatx4){0.f, 0.f, 0.f, 0.f};

#define PIPE_LOOP(NK, STAGE_AT)                                                \
  {                                                                            \
    STAGE_AT(0, 0);                                                            \
    STAGE_AT(1, 1);                                                            \
    int cur = 0, pf = 2;                                                       \
    _Pragma("unroll 1") for (int kt = 0; kt < (NK); ++kt) {                    \
      if (kt + 1 < (NK)) {                                                     \
        asm volatile("s_waitcnt vmcnt(4)" ::: "memory");                       \
      } else {                                                                 \
        asm volatile("s_waitcnt vmcnt(0)" ::: "memory");                       \
      }                                                                        \
      __builtin_amdgcn_sched_barrier(0);                                       \
      __builtin_amdgcn_s_barrier();                                            \
      __builtin_amdgcn_sched_barrier(0);                                       \
      if (kt + 2 < (NK)) STAGE_AT(pf, kt + 2);                                 \
      __builtin_amdgcn_sched_barrier(0);                                       \
      __builtin_amdgcn_s_setprio(1);                                           \
      GEMM_COMPUTE(cur);                                                       \
      __builtin_amdgcn_s_setprio(0);                                           \
      cur = (cur == 2) ? 0 : cur + 1;                                          \
      pf = (pf == 2) ? 0 : pf + 1;                                             \
    }                                                                          \
  }

// GT[b,u,s] = sum_p M[b,u,p] * PE[s,p]  (causal K-extent: p < 128*(s_t+1))
// Pair-block (s_t = pr, 15-pr); XCD pinned by b -> M[b] fetched into one L2.
__global__ __launch_bounds__(256) void k_gemm_gt(const ushort* __restrict__ M,
                                                 const ushort* __restrict__ PE,
                                                 ushort* __restrict__ GT) {
  int b, u_t, pr;
  xcd_map(blockIdx.x, &b, &u_t, &pr);
  const int u0 = u_t << 7;
  GEMM_PRELUDE();
  const ushort* a_base0 = M + ((size_t)((b << 9) + u0 + rr)) * TT + cg;
  const ushort* a_base1 = a_base0 + (size_t)64 * TT;
  floatx4 acc[4][4];
#pragma unroll 1
  for (int half = 0; half < 2; ++half) {
    const int s_t = half ? (15 - pr) : pr;
    const int s0 = s_t << 7;
    const int nk = (s_t << 2) + 4;
    const ushort* a_src0 = a_base0;
    const ushort* a_src1 = a_base1;
    const ushort* b_src0 = PE + (size_t)(s0 + rr) * TT + cg;
    const ushort* b_src1 = b_src0 + (size_t)64 * TT;
    ZERO_ACC();
#define SA_GT(c, k)                                                            \
  GEMM_STAGE(c, a_src0 + ((k) << 5), a_src1 + ((k) << 5), b_src0 + ((k) << 5), \
             b_src1 + ((k) << 5))
    PIPE_LOOP(nk, SA_GT);
#undef SA_GT
#pragma unroll
    for (int i = 0; i < 4; i++)
#pragma unroll
      for (int j = 0; j < 4; j++) {
        const int rowb = u0 + wm * 64 + i * 16 + quad * 4;
        const int col = s0 + wn * 64 + j * 16 + ln;
#pragma unroll
        for (int r = 0; r < 4; r++)
          GT[((size_t)((b << 9) + rowb + r)) * TT + col] = f2bf(acc[i][j][r]);
      }
    __syncthreads();  // slot-0/1 readers done before next half's re-stage
  }
}

// Pre-masked diagonal tiles: a2d[b][t_t][r][c] = (c<=r) ? GT[b, idx[b,t0+r], t0+c] : 0
__global__ __launch_bounds__(256) void k_diag(const int* __restrict__ idx,
                                              const ushort* __restrict__ GT,
                                              ushort* __restrict__ a2d) {
  const int t_t = blockIdx.x, b = blockIdx.y;
  const int t0 = t_t << 7;
  ushort* outt = a2d + (((size_t)(b << 4) + t_t) << 14);
  for (int e = threadIdx.x; e < 2048; e += 256) {
    const int r = e >> 4;
    const int c8 = (e & 15) << 3;
    const int u = idx[(b << 11) + t0 + r];
    const ushort* src = GT + ((size_t)((b << 9) + u)) * TT + t0 + c8;
    ushort4 lo = *(const ushort4*)(src);
    ushort4 hi = *(const ushort4*)(src + 4);
    ushort vals[8] = {lo.x, lo.y, lo.z, lo.w, hi.x, hi.y, hi.z, hi.w};
    ushort o[8];
#pragma unroll
    for (int k = 0; k < 8; ++k) o[k] = (c8 + k <= r) ? vals[k] : (ushort)0;
    *(ushort4*)(outt + r * 128 + c8) = *(ushort4*)&o[0];
    *(ushort4*)(outt + r * 128 + c8 + 4) = *(ushort4*)&o[4];
  }
}

// logits[b,t,j] = sum_{s<=t} GT[b, idx[b,t], s] * VvT[b,j,s]
// Pair-block (t_t = pr, 15-pr); XCD pinned by b -> GT[b]/VvT[b]/a2d[b]
// each fetched into exactly one L2. Per half, K-loop unified: kt < nk_main
// -> gathered GT rows; kt >= nk_main -> pre-masked diag tile.
__global__ __launch_bounds__(256) void k_gemm2(const int* __restrict__ idx,
                                               const ushort* __restrict__ GT,
                                               const ushort* __restrict__ a2d,
                                               const ushort* __restrict__ VvT,
                                               float* __restrict__ out) {
  int b, j_t, pr;
  xcd_map(blockIdx.x, &b, &j_t, &pr);
  const int j0 = j_t << 7;
  GEMM_PRELUDE();
  const ushort* b_base0 = VvT + ((size_t)((b << 9) + j0 + rr)) * TT + cg;
  const ushort* b_base1 = b_base0 + (size_t)64 * TT;
  floatx4 acc[4][4];
#pragma unroll 1
  for (int half = 0; half < 2; ++half) {
    const int t_t = half ? (15 - pr) : pr;
    const int t0 = t_t << 7;
    const int nk_main = t_t << 2;
    const int nk = nk_main + 4;
    const int u0 = idx[(b << 11) + t0 + rr];
    const int u1 = idx[(b << 11) + t0 + rr + 64];
    const ushort* a_src0 = GT + ((size_t)(b << 9) + u0) * TT + cg;
    const ushort* a_src1 = GT + ((size_t)(b << 9) + u1) * TT + cg;
    const ushort* b_src0 = b_base0;
    const ushort* b_src1 = b_base1;
    const ushort* ad0 =
        a2d + (((size_t)(b << 4) + t_t) << 14) + (size_t)rr * 128 + cg;
    const ushort* ad1 = ad0 + (size_t)64 * 128;
    ZERO_ACC();
#define SA_G2(c, k)                                                            \
  GEMM_STAGE(c,                                                                \
             (k) < nk_main ? a_src0 + ((k) << 5) : ad0 + (((k) - nk_main) << 5), \
             (k) < nk_main ? a_src1 + ((k) << 5) : ad1 + (((k) - nk_main) << 5), \
             b_src0 + ((k) << 5), b_src1 + ((k) << 5))
    PIPE_LOOP(nk, SA_G2);
#undef SA_G2
#pragma unroll
    for (int i = 0; i < 4; i++)
#pragma unroll
      for (int j = 0; j < 4; j++) {
        const int rowb = t0 + wm * 64 + i * 16 + quad * 4;
        const int col = j0 + wn * 64 + j * 16 + ln;
#pragma unroll
        for (int r = 0; r < 4; r++)
          out[((size_t)((b << 11) + rowb + r)) * VV + col] = acc[i][j][r];
      }
    __syncthreads();  // slot-0/1 readers done before next half's re-stage
  }
}

extern "C" void kernel_launch(void* const* d_in, const int* in_sizes, int n_in,
                              void* d_out, int out_size, void* d_ws, size_t ws_size,
                              hipStream_t stream) {
  const int* idx = (const int*)d_in[0];
  const float* pos_table = (const float*)d_in[1];
  const float* Wq = (const float*)d_in[2];
  const float* Wv = (const float*)d_in[3];
  float* out = (float*)d_out;

  char* ws = (char*)d_ws;
  // ws layout (bytes):
  //   WqT bf16 (V,V)        :         0 ..    524288
  //   PE  bf16 (T,T)        :    524288 ..   8912896
  //   M   bf16 (B,V,T)      :   8912896 ..  42467328
  //   VvT bf16 (B,V,T)      :  42467328 ..  76021760
  //   GT  bf16 (B,V,T)      :  76021760 .. 109576192
  //   a2d bf16 (B,16,128^2) : 109576192 .. 117964800
  ushort* WqT = (ushort*)(ws);
  ushort* PE = (ushort*)(ws + 524288UL);
  ushort* M = (ushort*)(ws + 8912896UL);
  ushort* VvT = (ushort*)(ws + 42467328UL);
  ushort* GT = (ushort*)(ws + 76021760UL);
  ushort* a2d = (ushort*)(ws + 109576192UL);

  k_transpose_wq<<<dim3(VV), 256, 0, stream>>>(Wq, WqT);
  k_build_pe<<<dim3(TT), 256, 0, stream>>>(pos_table, PE);
  k_build_mv<<<dim3(BB * VV), 256, 0, stream>>>(idx, Wv, WqT, M, VvT);
  k_gemm_gt<<<dim3(512), 256, 0, stream>>>(M, PE, GT);
  k_diag<<<dim3(16, BB), 256, 0, stream>>>(idx, GT, a2d);
  k_gemm2<<<dim3(512), 256, 0, stream>>>(idx, GT, a2d, VvT, out);
}